// Round 1
// 279.025 us; speedup vs baseline: 1.0979x; 1.0979x over previous
//
#include <hip/hip_runtime.h>
#include <math.h>

#define HIDDEN 128
#define MUL1   64
#define ACOLS  320   // HIDDEN + 3*MUL1
#define TBINS  4096

typedef unsigned short ushort_t;
typedef __attribute__((ext_vector_type(8))) short bf16x8;
typedef __attribute__((ext_vector_type(4))) float f32x4;

__device__ __forceinline__ unsigned bf16rne(float x) {
  const unsigned u = __float_as_uint(x);
  return (u + 0x7FFFu + ((u >> 16) & 1u)) >> 16;
}
__device__ __forceinline__ unsigned pack2(float a, float b) {
  return bf16rne(a) | (bf16rne(b) << 16);
}

// ---------------- K1: fused R_n table build (interleaved pairs) + receiver histogram
__global__ __launch_bounds__(128) void tab_hist(const float* __restrict__ W1,
                                                const float* __restrict__ W2,
                                                float* __restrict__ Tq,
                                                const int* __restrict__ recv,
                                                int* __restrict__ cnt, int n_edges) {
  const int tid = threadIdx.x;
  if (blockIdx.x > TBINS) {   // histogram blocks
    const int e = (blockIdx.x - (TBINS + 1)) * 128 + tid;
    if (e < n_edges) atomicAdd(&cnt[recv[e]], 1);
    return;
  }
  __shared__ float hsh[64];
  const int i = blockIdx.x;        // 0..TBINS
  const float x = (float)i * (5.0f / TBINS);
  if (tid < 64) {
    const bool valid = (x > 0.0f) && (x < 5.0f);
    const float invx = valid ? (1.0f / x) : 0.0f;
    float z = 0.0f;
#pragma unroll
    for (int r = 0; r < 8; ++r) {
      float arg = (float)(r + 1) * 0.6283185307f * x;     // k*pi*x/5
      float rad = 0.6324555320f * sinf(arg) * invx;       // sqrt(2/5)*sin/x
      z += rad * (W1[r * 64 + tid] * 0.3535533906f);      // W1/sqrt(8)
    }
    float sg = 1.0f / (1.0f + expf(-z));
    hsh[tid] = 1.679177f * z * sg;
  }
  __syncthreads();
  float acc = 0.0f;
  for (int j = 0; j < 64; ++j)
    acc += hsh[j] * W2[j * HIDDEN + tid];
  acc *= 0.125f;                                          // W2/8
  Tq[((size_t)i * HIDDEN + tid) * 2] = acc;               // row i as c=0
  if (i >= 1)
    Tq[((size_t)(i - 1) * HIDDEN + tid) * 2 + 1] = acc;   // row i as c=1 of i-1
}

// ---------------- K2a: per-block exclusive scan (1024 elems/block) ----------------
__global__ __launch_bounds__(1024) void scan_blocks(const int* __restrict__ cnt,
                                                    int* __restrict__ partial,
                                                    int* __restrict__ bsums, int n) {
  __shared__ int buf[1024];
  const int t = threadIdx.x;
  const int i = blockIdx.x * 1024 + t;
  const int v = (i < n) ? cnt[i] : 0;
  buf[t] = v;
  __syncthreads();
  for (int d = 1; d < 1024; d <<= 1) {
    const int x = buf[t];
    const int y = (t >= d) ? buf[t - d] : 0;
    __syncthreads();
    buf[t] = x + y;
    __syncthreads();
  }
  if (i < n) partial[i] = buf[t] - v;          // block-local exclusive
  if (t == 1023) bsums[blockIdx.x] = buf[1023];
}

// ---------------- K2b: single-block scan of block sums; writes off[n]=total ------
__global__ __launch_bounds__(1024) void scan_sums(int* __restrict__ bsums, int nb,
                                                  int* __restrict__ off, int n) {
  __shared__ int buf[1024];
  const int t = threadIdx.x;
  const int v = (t < nb) ? bsums[t] : 0;
  buf[t] = v;
  __syncthreads();
  for (int d = 1; d < 1024; d <<= 1) {
    const int x = buf[t];
    const int y = (t >= d) ? buf[t - d] : 0;
    __syncthreads();
    buf[t] = x + y;
    __syncthreads();
  }
  if (t < nb) bsums[t] = buf[t] - v;           // exclusive block offsets
  if (t == nb - 1) off[n] = buf[t];            // grand total
}

// ---------------- K2c: off/cur = partial + block offset ----------------
__global__ __launch_bounds__(256) void scan_final(const int* __restrict__ partial,
                                                  const int* __restrict__ bsums,
                                                  int* __restrict__ off,
                                                  int* __restrict__ cur, int n) {
  const int i = blockIdx.x * 256 + threadIdx.x;
  if (i < n) {
    const int o = partial[i] + bsums[i >> 10];
    off[i] = o;
    cur[i] = o;
  }
}

// ---------------- K3: build sorted 32B edge records ----------------
__global__ void scatter_kernel(const int* __restrict__ eidx,
                               const float* __restrict__ evec,
                               const float* __restrict__ elen,
                               int* __restrict__ cur, float4* __restrict__ recs,
                               int n_edges) {
  const int e = blockIdx.x * blockDim.x + threadIdx.x;
  if (e >= n_edges) return;
  const int s = eidx[e], r = eidx[n_edges + e];
  const float x = elen[e];
  const float v0 = evec[3 * e], v1 = evec[3 * e + 1], v2 = evec[3 * e + 2];
  const float rn = rsqrtf(v0 * v0 + v1 * v1 + v2 * v2);
  const float u = x * ((float)TBINS / 5.0f);
  int i0 = (int)floorf(u);
  i0 = i0 < 0 ? 0 : (i0 > TBINS - 1 ? TBINS - 1 : i0);
  const float fr = u - (float)i0;
  const bool valid = (x > 0.0f) && (x < 5.0f);
  const float w0 = valid ? 1.0f - fr : 0.0f;
  const float w1 = valid ? fr : 0.0f;
  const int pos = atomicAdd(&cur[r], 1);
  recs[2 * pos]     = make_float4(__int_as_float(s), w0, w1, __int_as_float(i0));
  recs[2 * pos + 1] = make_float4(1.7320508076f * v1 * rn,   // unit[:, [1,2,0]]*sqrt3
                                  1.7320508076f * v2 * rn,
                                  1.7320508076f * v0 * rn, 0.0f);
}

// ---------------- K4: pre-scale + hi/lo split weights into MFMA B-frag order ----
// P ushort layout: W0h[16384] W0l[16384] W1h[8192] W1l[8192] Wmh[24576] Wml[24576]
// frag element: P[base + ((nt*KF+q)*64 + lane)*8 + j] = W[(quad*8+j) + q*32][nt*16+col]
__global__ __launch_bounds__(256) void pack_weights(
    const float* __restrict__ W0, const float* __restrict__ W1,
    const float* __restrict__ Wm, ushort_t* __restrict__ P) {
  const int idx = blockIdx.x * 256 + threadIdx.x;     // 0..49151
  const int j = idx & 7, lane = (idx >> 3) & 63;
  const int krow = (lane >> 4) * 8 + j, col = lane & 15;
  float v; int hb, lb;
  if (idx < 16384) {
    const int tq = idx >> 9, nt = tq >> 2, q = tq & 3;
    v = W0[(krow + q * 32) * HIDDEN + nt * 16 + col] * 0.0883883476f;
    hb = idx; lb = idx + 16384;
  } else if (idx < 24576) {
    const int i2 = idx - 16384;
    const int tq = i2 >> 9, nt = tq >> 2, q = tq & 3;
    v = W1[(krow + q * 32) * MUL1 + nt * 16 + col] * 0.0883883476f;
    hb = 32768 + i2; lb = 40960 + i2;
  } else {
    const int i3 = idx - 24576;
    const int tq = i3 >> 9, nt = tq / 6, q = tq % 6;
    v = Wm[(krow + q * 32) * HIDDEN + nt * 16 + col] * 0.0721687836f;
    hb = 49152 + i3; lb = 73728 + i3;
  }
  const unsigned h = bf16rne(v);
  P[hb] = (ushort_t)h;
  P[lb] = (ushort_t)bf16rne(v - __uint_as_float(h << 16));
}

// ---------------- K5: pure gather: per node accumulate S (128) and G (128x3),
// write 1KB bf16 record. No LDS -> high occupancy for latency hiding.
__global__ __launch_bounds__(1024) void node_sg(
    const float* __restrict__ attrs, const float* __restrict__ Tq,
    const float4* __restrict__ recs, const int* __restrict__ off,
    unsigned* __restrict__ SG, int n_nodes) {
  const int lane = threadIdx.x & 63;
  const int wid = (blockIdx.x << 4) + (threadIdx.x >> 6);
  const int nw = gridDim.x << 4;
  const float2* attrs2 = (const float2*)attrs;
  for (int n = wid; n < n_nodes; n += nw) {
    const int beg = off[n], end = off[n + 1];
    float Sa = 0.f, Sb = 0.f;
    float Ga0 = 0.f, Ga1 = 0.f, Ga2 = 0.f, Gb0 = 0.f, Gb1 = 0.f, Gb2 = 0.f;
    for (int i = beg; i < end; i += 2) {
#pragma unroll
      for (int b = 0; b < 2; ++b) {
        const bool ok = (i + b) < end;
        const int idx = ok ? (i + b) : beg;       // clamp; zeroed via weights
        const float4 ra = recs[2 * idx];
        const float4 rb = recs[2 * idx + 1];
        const int s = __float_as_int(ra.x);
        const float w0 = ok ? ra.y : 0.f;
        const float w1v = ok ? ra.z : 0.f;
        const int i0 = __float_as_int(ra.w);
        const float4 tq = *(const float4*)&Tq[((size_t)i0 * HIDDEN + 2 * lane) * 2];
        const float2 av = attrs2[(size_t)s * 64 + lane];
        const float Ra = w0 * tq.x + w1v * tq.y;  // lerp ch 2l
        const float Rb = w0 * tq.z + w1v * tq.w;  // lerp ch 2l+1
        const float la = av.x * Ra, lb = av.y * Rb;
        Sa += la; Sb += lb;
        Ga0 += la * rb.x; Ga1 += la * rb.y; Ga2 += la * rb.z;
        Gb0 += lb * rb.x; Gb1 += lb * rb.y; Gb2 += lb * rb.z;
      }
    }
    unsigned* srow = SG + (size_t)n * 256;        // 256 u32 = 512 bf16 per node
    srow[lane]       = pack2(Sa, Sb);             // S[2l], S[2l+1]
    srow[64 + lane]  = pack2(Ga0, Gb0);           // G_d0
    srow[128 + lane] = pack2(Ga1, Gb1);           // G_d1
    srow[192 + lane] = pack2(Ga2, Gb2);           // G_d2
  }
}

// ---------------- K6: wave-per-16-nodes MFMA: A0=S@W0', A1=G@W1', B0, +=B0@Wm'
// 1-wave blocks (12.5 KB LDS), __launch_bounds__(64,2) -> up to 256 VGPR so the
// weight-fragment loads can be register double-buffered (ping-pong per nt/q
// chunk). Previous 104-VGPR version serialized ~192 L2-latency loads per wave.
__global__ __launch_bounds__(64, 2) void node_mfma(
    const ushort_t* __restrict__ SG, const ushort_t* __restrict__ P,
    float* __restrict__ out, int n_nodes) {
  __shared__ float B0s[16][196];      // B0 stage; stride 196 dw (2-way = free)
  const int lane = threadIdx.x & 63;
  const int tile = blockIdx.x;
  const int row = lane & 15, quad = lane >> 4;
  const int nA = min(tile * 16 + row, n_nodes - 1);   // clamped A-row node
  const ushort_t* sgA = SG + (size_t)nA * 512;
  const int cnode0 = tile * 16 + quad * 4;            // C-frag rows

  const ushort_t* W0h = P;
  const ushort_t* W0l = P + 16384;
  const ushort_t* W1h = P + 32768;
  const ushort_t* W1l = P + 40960;
  const ushort_t* Wmh = P + 49152;
  const ushort_t* Wml = P + 73728;

  // ---- A-side fragments (issued up front; S row + 3 G rows)
  bf16x8 aS[4], aG[3][4];
#pragma unroll
  for (int q = 0; q < 4; ++q)
    aS[q] = *(const bf16x8*)(sgA + quad * 8 + q * 32);
#pragma unroll
  for (int d = 0; d < 3; ++d)
#pragma unroll
    for (int q = 0; q < 4; ++q)
      aG[d][q] = *(const bf16x8*)(sgA + 128 + d * 128 + quad * 8 + q * 32);

  f32x4 c0[8];
#pragma unroll
  for (int nt = 0; nt < 8; ++nt) c0[nt] = (f32x4){0.f, 0.f, 0.f, 0.f};
  f32x4 c1[3][4];
#pragma unroll
  for (int d = 0; d < 3; ++d)
#pragma unroll
    for (int nt = 0; nt < 4; ++nt) c1[d][nt] = (f32x4){0.f, 0.f, 0.f, 0.f};

  // ---- Phase 1: A0 = S @ W0' (M=16, N=128, K=128), B split hi+lo.
  // Ping-pong prefetch: next nt's 8 fragments in flight while computing current.
  {
    bf16x8 ph[2][4], pl[2][4];
#pragma unroll
    for (int q = 0; q < 4; ++q) {
      const int fo = (q * 64 + lane) * 8;
      ph[0][q] = *(const bf16x8*)(W0h + fo);
      pl[0][q] = *(const bf16x8*)(W0l + fo);
    }
#pragma unroll
    for (int nt = 0; nt < 8; ++nt) {
      const int cur = nt & 1, nxt = cur ^ 1;
      if (nt < 7) {
#pragma unroll
        for (int q = 0; q < 4; ++q) {
          const int fo = (((nt + 1) * 4 + q) * 64 + lane) * 8;
          ph[nxt][q] = *(const bf16x8*)(W0h + fo);
          pl[nxt][q] = *(const bf16x8*)(W0l + fo);
        }
      }
#pragma unroll
      for (int q = 0; q < 4; ++q) {
        c0[nt] = __builtin_amdgcn_mfma_f32_16x16x32_bf16(aS[q], ph[cur][q], c0[nt], 0, 0, 0);
        c0[nt] = __builtin_amdgcn_mfma_f32_16x16x32_bf16(aS[q], pl[cur][q], c0[nt], 0, 0, 0);
      }
    }
  }

  // ---- Phase 2: A1_d = G_d @ W1' (3 x [M=16, N=64, K=128]), same ping-pong.
  {
    bf16x8 ph[2][4], pl[2][4];
#pragma unroll
    for (int q = 0; q < 4; ++q) {
      const int fo = (q * 64 + lane) * 8;
      ph[0][q] = *(const bf16x8*)(W1h + fo);
      pl[0][q] = *(const bf16x8*)(W1l + fo);
    }
#pragma unroll
    for (int nt = 0; nt < 4; ++nt) {
      const int cur = nt & 1, nxt = cur ^ 1;
      if (nt < 3) {
#pragma unroll
        for (int q = 0; q < 4; ++q) {
          const int fo = (((nt + 1) * 4 + q) * 64 + lane) * 8;
          ph[nxt][q] = *(const bf16x8*)(W1h + fo);
          pl[nxt][q] = *(const bf16x8*)(W1l + fo);
        }
      }
#pragma unroll
      for (int q = 0; q < 4; ++q)
#pragma unroll
        for (int d = 0; d < 3; ++d) {
          c1[d][nt] = __builtin_amdgcn_mfma_f32_16x16x32_bf16(aG[d][q], ph[cur][q], c1[d][nt], 0, 0, 0);
          c1[d][nt] = __builtin_amdgcn_mfma_f32_16x16x32_bf16(aG[d][q], pl[cur][q], c1[d][nt], 0, 0, 0);
        }
    }
  }

  // ---- store A1 (out cols 128 + 3m + d) and build B0 in LDS (C- -> A-layout)
#pragma unroll
  for (int d = 0; d < 3; ++d)
#pragma unroll
    for (int nt = 0; nt < 4; ++nt) {
      const int m = nt * 16 + row;
#pragma unroll
      for (int r = 0; r < 4; ++r) {
        const int n = cnode0 + r;
        if (n < n_nodes) out[(size_t)n * ACOLS + HIDDEN + 3 * m + d] = c1[d][nt][r];
      }
    }
#pragma unroll
  for (int nt = 0; nt < 8; ++nt)
#pragma unroll
    for (int r = 0; r < 4; ++r) {
      const float a = c0[nt][r];
      B0s[quad * 4 + r][nt * 16 + row] = a * a;
    }
#pragma unroll
  for (int nt = 0; nt < 4; ++nt)
#pragma unroll
    for (int r = 0; r < 4; ++r) {
      const float x = c1[0][nt][r], y = c1[1][nt][r], z = c1[2][nt][r];
      B0s[quad * 4 + r][HIDDEN + nt * 16 + row] =
          (x * x + y * y + z * z) * 0.5773502692f;   // /sqrt(3)
    }

  // ---- Phase 3: mix c0 += B0 @ Wm' (K=192), A split hi/lo in-register (3-term).
  // Prefetch q=0's 16 fragments BEFORE the barrier; ping-pong per q after.
  bf16x8 mh[2][8], ml[2][8];
#pragma unroll
  for (int nt = 0; nt < 8; ++nt) {
    const int fo = ((nt * 6) * 64 + lane) * 8;
    mh[0][nt] = *(const bf16x8*)(Wmh + fo);
    ml[0][nt] = *(const bf16x8*)(Wml + fo);
  }
  __syncthreads();
  {
#pragma unroll
    for (int q = 0; q < 6; ++q) {
      const int cur = q & 1, nxt = cur ^ 1;
      if (q < 5) {
#pragma unroll
        for (int nt = 0; nt < 8; ++nt) {
          const int fo = ((nt * 6 + (q + 1)) * 64 + lane) * 8;
          mh[nxt][nt] = *(const bf16x8*)(Wmh + fo);
          ml[nxt][nt] = *(const bf16x8*)(Wml + fo);
        }
      }
      const float* src = &B0s[row][quad * 8 + q * 32];
      bf16x8 ah, al;
#pragma unroll
      for (int j = 0; j < 8; ++j) {
        const float v = src[j];
        const unsigned h = bf16rne(v);
        ah[j] = (short)h;
        al[j] = (short)bf16rne(v - __uint_as_float(h << 16));
      }
#pragma unroll
      for (int nt = 0; nt < 8; ++nt) {
        c0[nt] = __builtin_amdgcn_mfma_f32_16x16x32_bf16(ah, mh[cur][nt], c0[nt], 0, 0, 0);
        c0[nt] = __builtin_amdgcn_mfma_f32_16x16x32_bf16(al, mh[cur][nt], c0[nt], 0, 0, 0);
        c0[nt] = __builtin_amdgcn_mfma_f32_16x16x32_bf16(ah, ml[cur][nt], c0[nt], 0, 0, 0);
      }
    }
  }

  // ---- store out[:, :128] = A0 + mix0
#pragma unroll
  for (int nt = 0; nt < 8; ++nt)
#pragma unroll
    for (int r = 0; r < 4; ++r) {
      const int n = cnode0 + r;
      if (n < n_nodes) out[(size_t)n * ACOLS + nt * 16 + row] = c0[nt][r];
    }
}

extern "C" void kernel_launch(void* const* d_in, const int* in_sizes, int n_in,
                              void* d_out, int out_size, void* d_ws, size_t ws_size,
                              hipStream_t stream) {
  const float* attrs = (const float*)d_in[0];
  const int*   eidx  = (const int*)d_in[1];
  const float* evec  = (const float*)d_in[2];
  const float* elen  = (const float*)d_in[3];
  const float* W1    = (const float*)d_in[4];
  const float* W2    = (const float*)d_in[5];
  const float* Wtp0  = (const float*)d_in[6];
  const float* Wtp1  = (const float*)d_in[7];
  const float* Wmix  = (const float*)d_in[8];
  float* out = (float*)d_out;

  const int n_nodes = in_sizes[0] / HIDDEN;
  const int n_edges = in_sizes[1] / 2;

  // ws: recs | Tq | cnt | off | cur | partial | bsums | SG(1KB/node) | P(192KB)
  char* ws = (char*)d_ws;
  float4* recs = (float4*)ws;
  size_t o1 = (((size_t)n_edges * 32) + 255) & ~(size_t)255;
  float* Tq = (float*)(ws + o1);
  size_t o2 = (o1 + (size_t)(TBINS + 1) * HIDDEN * 2 * 4 + 255) & ~(size_t)255;
  int* cnt = (int*)(ws + o2);
  size_t o3 = (o2 + (size_t)n_nodes * 4 + 255) & ~(size_t)255;
  int* off = (int*)(ws + o3);
  size_t o4 = (o3 + (size_t)(n_nodes + 1) * 4 + 255) & ~(size_t)255;
  int* cur = (int*)(ws + o4);
  size_t o5 = (o4 + (size_t)n_nodes * 4 + 255) & ~(size_t)255;
  int* partial = (int*)(ws + o5);
  size_t o6 = (o5 + (size_t)n_nodes * 4 + 255) & ~(size_t)255;
  int* bsums = (int*)(ws + o6);
  size_t o7 = (o6 + 1024 * 4 + 255) & ~(size_t)255;
  unsigned* SG = (unsigned*)(ws + o7);
  size_t o8 = o7 + (size_t)n_nodes * 1024;
  ushort_t* P = (ushort_t*)(ws + o8);

  (void)hipMemsetAsync(cnt, 0, (size_t)n_nodes * 4, stream);
  const int hist_blocks = (n_edges + 127) / 128;
  tab_hist<<<TBINS + 1 + hist_blocks, 128, 0, stream>>>(W1, W2, Tq,
                                                        eidx + n_edges, cnt, n_edges);
  const int nscan = (n_nodes + 1023) / 1024;
  scan_blocks<<<nscan, 1024, 0, stream>>>(cnt, partial, bsums, n_nodes);
  scan_sums<<<1, 1024, 0, stream>>>(bsums, nscan, off, n_nodes);
  scan_final<<<(n_nodes + 255) / 256, 256, 0, stream>>>(partial, bsums, off, cur,
                                                        n_nodes);
  scatter_kernel<<<(n_edges + 255) / 256, 256, 0, stream>>>(eidx, evec, elen, cur,
                                                            recs, n_edges);
  pack_weights<<<192, 256, 0, stream>>>(Wtp0, Wtp1, Wmix, P);
  node_sg<<<512, 1024, 0, stream>>>(attrs, Tq, recs, off, SG, n_nodes);
  const int ntiles = (n_nodes + 15) / 16;
  node_mfma<<<ntiles, 64, 0, stream>>>((const ushort_t*)SG, P, out, n_nodes);
}

// Round 2
// 269.609 us; speedup vs baseline: 1.1362x; 1.0349x over previous
//
#include <hip/hip_runtime.h>
#include <math.h>

#define HIDDEN 128
#define MUL1   64
#define ACOLS  320   // HIDDEN + 3*MUL1
#define TBINS  4096

typedef unsigned short ushort_t;
typedef __attribute__((ext_vector_type(8))) short bf16x8;
typedef __attribute__((ext_vector_type(4))) float f32x4;

__device__ __forceinline__ unsigned bf16rne(float x) {
  const unsigned u = __float_as_uint(x);
  return (u + 0x7FFFu + ((u >> 16) & 1u)) >> 16;
}
__device__ __forceinline__ unsigned pack2(float a, float b) {
  return bf16rne(a) | (bf16rne(b) << 16);
}
__device__ __forceinline__ float bflo(unsigned u) {   // low bf16 -> f32
  return __uint_as_float(u << 16);
}
__device__ __forceinline__ float bfhi(unsigned u) {   // high bf16 -> f32
  return __uint_as_float(u & 0xffff0000u);
}

// ---------------- K1: fused R_n table (packed bf16 lerp pairs) + receiver histogram
// TqB u32 layout: TqB[i*128+ch] = { lo: val(i,ch), hi: val(i+1,ch) }
__global__ __launch_bounds__(128) void tab_hist(const float* __restrict__ W1,
                                                const float* __restrict__ W2,
                                                ushort_t* __restrict__ TqB,
                                                const int* __restrict__ recv,
                                                int* __restrict__ cnt, int n_edges) {
  const int tid = threadIdx.x;
  if (blockIdx.x > TBINS) {   // histogram blocks
    const int e = (blockIdx.x - (TBINS + 1)) * 128 + tid;
    if (e < n_edges) atomicAdd(&cnt[recv[e]], 1);
    return;
  }
  __shared__ float hsh[64];
  const int i = blockIdx.x;        // 0..TBINS
  const float x = (float)i * (5.0f / TBINS);
  if (tid < 64) {
    const bool valid = (x > 0.0f) && (x < 5.0f);
    const float invx = valid ? (1.0f / x) : 0.0f;
    float z = 0.0f;
#pragma unroll
    for (int r = 0; r < 8; ++r) {
      float arg = (float)(r + 1) * 0.6283185307f * x;     // k*pi*x/5
      float rad = 0.6324555320f * sinf(arg) * invx;       // sqrt(2/5)*sin/x
      z += rad * (W1[r * 64 + tid] * 0.3535533906f);      // W1/sqrt(8)
    }
    float sg = 1.0f / (1.0f + expf(-z));
    hsh[tid] = 1.679177f * z * sg;
  }
  __syncthreads();
  float acc = 0.0f;
  for (int j = 0; j < 64; ++j)
    acc += hsh[j] * W2[j * HIDDEN + tid];
  acc *= 0.125f;                                          // W2/8
  const ushort_t a16 = (ushort_t)bf16rne(acc);
  TqB[((size_t)i * HIDDEN + tid) * 2] = a16;              // lo slot of row i
  if (i >= 1)
    TqB[((size_t)(i - 1) * HIDDEN + tid) * 2 + 1] = a16;  // hi slot of row i-1
}

// ---------------- K1b: pack node_attrs f32 -> bf16x2 (halves gather traffic) ----
__global__ __launch_bounds__(256) void attrs_pack(const float* __restrict__ attrs,
                                                  unsigned* __restrict__ attrsB,
                                                  int n2) {
  const int i = blockIdx.x * 256 + threadIdx.x;
  if (i < n2) {
    const float2 v = ((const float2*)attrs)[i];
    attrsB[i] = pack2(v.x, v.y);
  }
}

// ---------------- K2a: per-block exclusive scan (1024 elems/block) ----------------
__global__ __launch_bounds__(1024) void scan_blocks(const int* __restrict__ cnt,
                                                    int* __restrict__ partial,
                                                    int* __restrict__ bsums, int n) {
  __shared__ int buf[1024];
  const int t = threadIdx.x;
  const int i = blockIdx.x * 1024 + t;
  const int v = (i < n) ? cnt[i] : 0;
  buf[t] = v;
  __syncthreads();
  for (int d = 1; d < 1024; d <<= 1) {
    const int x = buf[t];
    const int y = (t >= d) ? buf[t - d] : 0;
    __syncthreads();
    buf[t] = x + y;
    __syncthreads();
  }
  if (i < n) partial[i] = buf[t] - v;          // block-local exclusive
  if (t == 1023) bsums[blockIdx.x] = buf[1023];
}

// ---------------- K2b: single-block scan of block sums; writes off[n]=total ------
__global__ __launch_bounds__(1024) void scan_sums(int* __restrict__ bsums, int nb,
                                                  int* __restrict__ off, int n) {
  __shared__ int buf[1024];
  const int t = threadIdx.x;
  const int v = (t < nb) ? bsums[t] : 0;
  buf[t] = v;
  __syncthreads();
  for (int d = 1; d < 1024; d <<= 1) {
    const int x = buf[t];
    const int y = (t >= d) ? buf[t - d] : 0;
    __syncthreads();
    buf[t] = x + y;
    __syncthreads();
  }
  if (t < nb) bsums[t] = buf[t] - v;           // exclusive block offsets
  if (t == nb - 1) off[n] = buf[t];            // grand total
}

// ---------------- K2c: off/cur = partial + block offset ----------------
__global__ __launch_bounds__(256) void scan_final(const int* __restrict__ partial,
                                                  const int* __restrict__ bsums,
                                                  int* __restrict__ off,
                                                  int* __restrict__ cur, int n) {
  const int i = blockIdx.x * 256 + threadIdx.x;
  if (i < n) {
    const int o = partial[i] + bsums[i >> 10];
    off[i] = o;
    cur[i] = o;
  }
}

// ---------------- K3: build sorted 32B edge records ----------------
__global__ void scatter_kernel(const int* __restrict__ eidx,
                               const float* __restrict__ evec,
                               const float* __restrict__ elen,
                               int* __restrict__ cur, float4* __restrict__ recs,
                               int n_edges) {
  const int e = blockIdx.x * blockDim.x + threadIdx.x;
  if (e >= n_edges) return;
  const int s = eidx[e], r = eidx[n_edges + e];
  const float x = elen[e];
  const float v0 = evec[3 * e], v1 = evec[3 * e + 1], v2 = evec[3 * e + 2];
  const float rn = rsqrtf(v0 * v0 + v1 * v1 + v2 * v2);
  const float u = x * ((float)TBINS / 5.0f);
  int i0 = (int)floorf(u);
  i0 = i0 < 0 ? 0 : (i0 > TBINS - 1 ? TBINS - 1 : i0);
  const float fr = u - (float)i0;
  const bool valid = (x > 0.0f) && (x < 5.0f);
  const float w0 = valid ? 1.0f - fr : 0.0f;
  const float w1 = valid ? fr : 0.0f;
  const int pos = atomicAdd(&cur[r], 1);
  recs[2 * pos]     = make_float4(__int_as_float(s), w0, w1, __int_as_float(i0));
  recs[2 * pos + 1] = make_float4(1.7320508076f * v1 * rn,   // unit[:, [1,2,0]]*sqrt3
                                  1.7320508076f * v2 * rn,
                                  1.7320508076f * v0 * rn, 0.0f);
}

// ---------------- K4: pre-scale + hi/lo split weights into MFMA B-frag order ----
// P ushort layout: W0h[16384] W0l[16384] W1h[8192] W1l[8192] Wmh[24576] Wml[24576]
// frag element: P[base + ((nt*KF+q)*64 + lane)*8 + j] = W[(quad*8+j) + q*32][nt*16+col]
__global__ __launch_bounds__(256) void pack_weights(
    const float* __restrict__ W0, const float* __restrict__ W1,
    const float* __restrict__ Wm, ushort_t* __restrict__ P) {
  const int idx = blockIdx.x * 256 + threadIdx.x;     // 0..49151
  const int j = idx & 7, lane = (idx >> 3) & 63;
  const int krow = (lane >> 4) * 8 + j, col = lane & 15;
  float v; int hb, lb;
  if (idx < 16384) {
    const int tq = idx >> 9, nt = tq >> 2, q = tq & 3;
    v = W0[(krow + q * 32) * HIDDEN + nt * 16 + col] * 0.0883883476f;
    hb = idx; lb = idx + 16384;
  } else if (idx < 24576) {
    const int i2 = idx - 16384;
    const int tq = i2 >> 9, nt = tq >> 2, q = tq & 3;
    v = W1[(krow + q * 32) * MUL1 + nt * 16 + col] * 0.0883883476f;
    hb = 32768 + i2; lb = 40960 + i2;
  } else {
    const int i3 = idx - 24576;
    const int tq = i3 >> 9, nt = tq / 6, q = tq % 6;
    v = Wm[(krow + q * 32) * HIDDEN + nt * 16 + col] * 0.0721687836f;
    hb = 49152 + i3; lb = 73728 + i3;
  }
  const unsigned h = bf16rne(v);
  P[hb] = (ushort_t)h;
  P[lb] = (ushort_t)bf16rne(v - __uint_as_float(h << 16));
}

// ---------------- K5: pure gather: per node accumulate S (128) and G (128x3),
// write 1KB bf16 record. bf16 attrs + bf16 lerp table halve gather bytes/edge.
__global__ __launch_bounds__(1024) void node_sg(
    const unsigned* __restrict__ attrsB, const unsigned* __restrict__ TqB,
    const float4* __restrict__ recs, const int* __restrict__ off,
    unsigned* __restrict__ SG, int n_nodes) {
  const int lane = threadIdx.x & 63;
  const int wid = (blockIdx.x << 4) + (threadIdx.x >> 6);
  const int nw = gridDim.x << 4;
  for (int n = wid; n < n_nodes; n += nw) {
    const int beg = off[n], end = off[n + 1];
    float Sa = 0.f, Sb = 0.f;
    float Ga0 = 0.f, Ga1 = 0.f, Ga2 = 0.f, Gb0 = 0.f, Gb1 = 0.f, Gb2 = 0.f;
    for (int i = beg; i < end; i += 2) {
#pragma unroll
      for (int b = 0; b < 2; ++b) {
        const bool ok = (i + b) < end;
        const int idx = ok ? (i + b) : beg;       // clamp; zeroed via weights
        const float4 ra = recs[2 * idx];
        const float4 rb = recs[2 * idx + 1];
        const int s = __float_as_int(ra.x);
        const float w0 = ok ? ra.y : 0.f;
        const float w1v = ok ? ra.z : 0.f;
        const int i0 = __float_as_int(ra.w);
        const uint2 tq = *(const uint2*)&TqB[(size_t)i0 * HIDDEN + 2 * lane];
        const unsigned av = attrsB[(size_t)s * 64 + lane];
        const float Ra = w0 * bflo(tq.x) + w1v * bfhi(tq.x);  // lerp ch 2l
        const float Rb = w0 * bflo(tq.y) + w1v * bfhi(tq.y);  // lerp ch 2l+1
        const float la = bflo(av) * Ra, lb = bfhi(av) * Rb;
        Sa += la; Sb += lb;
        Ga0 += la * rb.x; Ga1 += la * rb.y; Ga2 += la * rb.z;
        Gb0 += lb * rb.x; Gb1 += lb * rb.y; Gb2 += lb * rb.z;
      }
    }
    unsigned* srow = SG + (size_t)n * 256;        // 256 u32 = 512 bf16 per node
    srow[lane]       = pack2(Sa, Sb);             // S[2l], S[2l+1]
    srow[64 + lane]  = pack2(Ga0, Gb0);           // G_d0
    srow[128 + lane] = pack2(Ga1, Gb1);           // G_d1
    srow[192 + lane] = pack2(Ga2, Gb2);           // G_d2
  }
}

// ---------------- K6: wave-per-16-nodes MFMA: A0=S@W0', A1=G@W1', B0, +=B0@Wm'
// 1-wave blocks (12.5 KB LDS), __launch_bounds__(64,2) -> up to 256 VGPR so the
// weight-fragment loads can be register double-buffered (ping-pong per nt/q
// chunk).
__global__ __launch_bounds__(64, 2) void node_mfma(
    const ushort_t* __restrict__ SG, const ushort_t* __restrict__ P,
    float* __restrict__ out, int n_nodes) {
  __shared__ float B0s[16][196];      // B0 stage; stride 196 dw (2-way = free)
  const int lane = threadIdx.x & 63;
  const int tile = blockIdx.x;
  const int row = lane & 15, quad = lane >> 4;
  const int nA = min(tile * 16 + row, n_nodes - 1);   // clamped A-row node
  const ushort_t* sgA = SG + (size_t)nA * 512;
  const int cnode0 = tile * 16 + quad * 4;            // C-frag rows

  const ushort_t* W0h = P;
  const ushort_t* W0l = P + 16384;
  const ushort_t* W1h = P + 32768;
  const ushort_t* W1l = P + 40960;
  const ushort_t* Wmh = P + 49152;
  const ushort_t* Wml = P + 73728;

  // ---- A-side fragments (issued up front; S row + 3 G rows)
  bf16x8 aS[4], aG[3][4];
#pragma unroll
  for (int q = 0; q < 4; ++q)
    aS[q] = *(const bf16x8*)(sgA + quad * 8 + q * 32);
#pragma unroll
  for (int d = 0; d < 3; ++d)
#pragma unroll
    for (int q = 0; q < 4; ++q)
      aG[d][q] = *(const bf16x8*)(sgA + 128 + d * 128 + quad * 8 + q * 32);

  f32x4 c0[8];
#pragma unroll
  for (int nt = 0; nt < 8; ++nt) c0[nt] = (f32x4){0.f, 0.f, 0.f, 0.f};
  f32x4 c1[3][4];
#pragma unroll
  for (int d = 0; d < 3; ++d)
#pragma unroll
    for (int nt = 0; nt < 4; ++nt) c1[d][nt] = (f32x4){0.f, 0.f, 0.f, 0.f};

  // ---- Phase 1: A0 = S @ W0' (M=16, N=128, K=128), B split hi+lo.
  // Ping-pong prefetch: next nt's 8 fragments in flight while computing current.
  {
    bf16x8 ph[2][4], pl[2][4];
#pragma unroll
    for (int q = 0; q < 4; ++q) {
      const int fo = (q * 64 + lane) * 8;
      ph[0][q] = *(const bf16x8*)(W0h + fo);
      pl[0][q] = *(const bf16x8*)(W0l + fo);
    }
#pragma unroll
    for (int nt = 0; nt < 8; ++nt) {
      const int cur = nt & 1, nxt = cur ^ 1;
      if (nt < 7) {
#pragma unroll
        for (int q = 0; q < 4; ++q) {
          const int fo = (((nt + 1) * 4 + q) * 64 + lane) * 8;
          ph[nxt][q] = *(const bf16x8*)(W0h + fo);
          pl[nxt][q] = *(const bf16x8*)(W0l + fo);
        }
      }
#pragma unroll
      for (int q = 0; q < 4; ++q) {
        c0[nt] = __builtin_amdgcn_mfma_f32_16x16x32_bf16(aS[q], ph[cur][q], c0[nt], 0, 0, 0);
        c0[nt] = __builtin_amdgcn_mfma_f32_16x16x32_bf16(aS[q], pl[cur][q], c0[nt], 0, 0, 0);
      }
    }
  }

  // ---- Phase 2: A1_d = G_d @ W1' (3 x [M=16, N=64, K=128]), same ping-pong.
  {
    bf16x8 ph[2][4], pl[2][4];
#pragma unroll
    for (int q = 0; q < 4; ++q) {
      const int fo = (q * 64 + lane) * 8;
      ph[0][q] = *(const bf16x8*)(W1h + fo);
      pl[0][q] = *(const bf16x8*)(W1l + fo);
    }
#pragma unroll
    for (int nt = 0; nt < 4; ++nt) {
      const int cur = nt & 1, nxt = cur ^ 1;
      if (nt < 3) {
#pragma unroll
        for (int q = 0; q < 4; ++q) {
          const int fo = (((nt + 1) * 4 + q) * 64 + lane) * 8;
          ph[nxt][q] = *(const bf16x8*)(W1h + fo);
          pl[nxt][q] = *(const bf16x8*)(W1l + fo);
        }
      }
#pragma unroll
      for (int q = 0; q < 4; ++q)
#pragma unroll
        for (int d = 0; d < 3; ++d) {
          c1[d][nt] = __builtin_amdgcn_mfma_f32_16x16x32_bf16(aG[d][q], ph[cur][q], c1[d][nt], 0, 0, 0);
          c1[d][nt] = __builtin_amdgcn_mfma_f32_16x16x32_bf16(aG[d][q], pl[cur][q], c1[d][nt], 0, 0, 0);
        }
    }
  }

  // ---- store A1 (out cols 128 + 3m + d) and build B0 in LDS (C- -> A-layout)
#pragma unroll
  for (int d = 0; d < 3; ++d)
#pragma unroll
    for (int nt = 0; nt < 4; ++nt) {
      const int m = nt * 16 + row;
#pragma unroll
      for (int r = 0; r < 4; ++r) {
        const int n = cnode0 + r;
        if (n < n_nodes) out[(size_t)n * ACOLS + HIDDEN + 3 * m + d] = c1[d][nt][r];
      }
    }
#pragma unroll
  for (int nt = 0; nt < 8; ++nt)
#pragma unroll
    for (int r = 0; r < 4; ++r) {
      const float a = c0[nt][r];
      B0s[quad * 4 + r][nt * 16 + row] = a * a;
    }
#pragma unroll
  for (int nt = 0; nt < 4; ++nt)
#pragma unroll
    for (int r = 0; r < 4; ++r) {
      const float x = c1[0][nt][r], y = c1[1][nt][r], z = c1[2][nt][r];
      B0s[quad * 4 + r][HIDDEN + nt * 16 + row] =
          (x * x + y * y + z * z) * 0.5773502692f;   // /sqrt(3)
    }

  // ---- Phase 3: mix c0 += B0 @ Wm' (K=192), A split hi/lo in-register (3-term).
  // Prefetch q=0's 16 fragments BEFORE the barrier; ping-pong per q after.
  bf16x8 mh[2][8], ml[2][8];
#pragma unroll
  for (int nt = 0; nt < 8; ++nt) {
    const int fo = ((nt * 6) * 64 + lane) * 8;
    mh[0][nt] = *(const bf16x8*)(Wmh + fo);
    ml[0][nt] = *(const bf16x8*)(Wml + fo);
  }
  __syncthreads();
  {
#pragma unroll
    for (int q = 0; q < 6; ++q) {
      const int cur = q & 1, nxt = cur ^ 1;
      if (q < 5) {
#pragma unroll
        for (int nt = 0; nt < 8; ++nt) {
          const int fo = ((nt * 6 + (q + 1)) * 64 + lane) * 8;
          mh[nxt][nt] = *(const bf16x8*)(Wmh + fo);
          ml[nxt][nt] = *(const bf16x8*)(Wml + fo);
        }
      }
      const float* src = &B0s[row][quad * 8 + q * 32];
      bf16x8 ah, al;
#pragma unroll
      for (int j = 0; j < 8; ++j) {
        const float v = src[j];
        const unsigned h = bf16rne(v);
        ah[j] = (short)h;
        al[j] = (short)bf16rne(v - __uint_as_float(h << 16));
      }
#pragma unroll
      for (int nt = 0; nt < 8; ++nt) {
        c0[nt] = __builtin_amdgcn_mfma_f32_16x16x32_bf16(ah, mh[cur][nt], c0[nt], 0, 0, 0);
        c0[nt] = __builtin_amdgcn_mfma_f32_16x16x32_bf16(al, mh[cur][nt], c0[nt], 0, 0, 0);
        c0[nt] = __builtin_amdgcn_mfma_f32_16x16x32_bf16(ah, ml[cur][nt], c0[nt], 0, 0, 0);
      }
    }
  }

  // ---- store out[:, :128] = A0 + mix0
#pragma unroll
  for (int nt = 0; nt < 8; ++nt)
#pragma unroll
    for (int r = 0; r < 4; ++r) {
      const int n = cnode0 + r;
      if (n < n_nodes) out[(size_t)n * ACOLS + nt * 16 + row] = c0[nt][r];
    }
}

extern "C" void kernel_launch(void* const* d_in, const int* in_sizes, int n_in,
                              void* d_out, int out_size, void* d_ws, size_t ws_size,
                              hipStream_t stream) {
  const float* attrs = (const float*)d_in[0];
  const int*   eidx  = (const int*)d_in[1];
  const float* evec  = (const float*)d_in[2];
  const float* elen  = (const float*)d_in[3];
  const float* W1    = (const float*)d_in[4];
  const float* W2    = (const float*)d_in[5];
  const float* Wtp0  = (const float*)d_in[6];
  const float* Wtp1  = (const float*)d_in[7];
  const float* Wmix  = (const float*)d_in[8];
  float* out = (float*)d_out;

  const int n_nodes = in_sizes[0] / HIDDEN;
  const int n_edges = in_sizes[1] / 2;

  // ws: recs | TqB | cnt | off | cur | partial | bsums | SG(1KB/node) | P | attrsB
  char* ws = (char*)d_ws;
  float4* recs = (float4*)ws;
  size_t o1 = (((size_t)n_edges * 32) + 255) & ~(size_t)255;
  ushort_t* TqB = (ushort_t*)(ws + o1);                       // (TBINS+1)*128 u32
  size_t o2 = (o1 + (size_t)(TBINS + 1) * HIDDEN * 4 + 255) & ~(size_t)255;
  int* cnt = (int*)(ws + o2);
  size_t o3 = (o2 + (size_t)n_nodes * 4 + 255) & ~(size_t)255;
  int* off = (int*)(ws + o3);
  size_t o4 = (o3 + (size_t)(n_nodes + 1) * 4 + 255) & ~(size_t)255;
  int* cur = (int*)(ws + o4);
  size_t o5 = (o4 + (size_t)n_nodes * 4 + 255) & ~(size_t)255;
  int* partial = (int*)(ws + o5);
  size_t o6 = (o5 + (size_t)n_nodes * 4 + 255) & ~(size_t)255;
  int* bsums = (int*)(ws + o6);
  size_t o7 = (o6 + 1024 * 4 + 255) & ~(size_t)255;
  unsigned* SG = (unsigned*)(ws + o7);
  size_t o8 = o7 + (size_t)n_nodes * 1024;
  ushort_t* P = (ushort_t*)(ws + o8);
  size_t o9 = (o8 + 98304 * 2 + 255) & ~(size_t)255;
  unsigned* attrsB = (unsigned*)(ws + o9);                    // n_nodes*64 u32

  (void)hipMemsetAsync(cnt, 0, (size_t)n_nodes * 4, stream);
  const int n2 = n_nodes * 64;
  attrs_pack<<<(n2 + 255) / 256, 256, 0, stream>>>(attrs, attrsB, n2);
  const int hist_blocks = (n_edges + 127) / 128;
  tab_hist<<<TBINS + 1 + hist_blocks, 128, 0, stream>>>(W1, W2, TqB,
                                                        eidx + n_edges, cnt, n_edges);
  const int nscan = (n_nodes + 1023) / 1024;
  scan_blocks<<<nscan, 1024, 0, stream>>>(cnt, partial, bsums, n_nodes);
  scan_sums<<<1, 1024, 0, stream>>>(bsums, nscan, off, n_nodes);
  scan_final<<<(n_nodes + 255) / 256, 256, 0, stream>>>(partial, bsums, off, cur,
                                                        n_nodes);
  scatter_kernel<<<(n_edges + 255) / 256, 256, 0, stream>>>(eidx, evec, elen, cur,
                                                            recs, n_edges);
  pack_weights<<<192, 256, 0, stream>>>(Wtp0, Wtp1, Wmix, P);
  node_sg<<<512, 1024, 0, stream>>>(attrsB, (const unsigned*)TqB, recs, off, SG,
                                    n_nodes);
  const int ntiles = (n_nodes + 15) / 16;
  node_mfma<<<ntiles, 64, 0, stream>>>((const ushort_t*)SG, P, out, n_nodes);
}

// Round 4
// 242.649 us; speedup vs baseline: 1.2625x; 1.1111x over previous
//
#include <hip/hip_runtime.h>
#include <math.h>

#define HIDDEN 128
#define MUL1   64
#define ACOLS  320   // HIDDEN + 3*MUL1
#define TBINS  4096

typedef unsigned short ushort_t;
typedef __attribute__((ext_vector_type(8))) _Float16 f16x8;
typedef __attribute__((ext_vector_type(4))) float f32x4;

__device__ __forceinline__ unsigned short f2h(float x) {
  return __builtin_bit_cast(unsigned short, (_Float16)x);
}
__device__ __forceinline__ unsigned pack2h(float a, float b) {
  return (unsigned)f2h(a) | ((unsigned)f2h(b) << 16);
}
__device__ __forceinline__ float hlo(unsigned u) {
  return (float)__builtin_bit_cast(_Float16, (unsigned short)(u & 0xffffu));
}
__device__ __forceinline__ float hhi(unsigned u) {
  return (float)__builtin_bit_cast(_Float16, (unsigned short)(u >> 16));
}

// ---------------- K1: fused R_n table (packed fp16 lerp pairs) + receiver histogram
// Tq u32 entry (i*128+ch) = { lo fp16: val(i,ch), hi fp16: val(i+1,ch) }
__global__ __launch_bounds__(128) void tab_hist(const float* __restrict__ W1,
                                                const float* __restrict__ W2,
                                                ushort_t* __restrict__ TqB,
                                                const int* __restrict__ recv,
                                                int* __restrict__ cnt, int n_edges) {
  const int tid = threadIdx.x;
  if (blockIdx.x > TBINS) {   // histogram blocks
    const int e = (blockIdx.x - (TBINS + 1)) * 128 + tid;
    if (e < n_edges) atomicAdd(&cnt[recv[e]], 1);
    return;
  }
  __shared__ float hsh[64];
  const int i = blockIdx.x;        // 0..TBINS
  const float x = (float)i * (5.0f / TBINS);
  if (tid < 64) {
    const bool valid = (x > 0.0f) && (x < 5.0f);
    const float invx = valid ? (1.0f / x) : 0.0f;
    float z = 0.0f;
#pragma unroll
    for (int r = 0; r < 8; ++r) {
      float arg = (float)(r + 1) * 0.6283185307f * x;     // k*pi*x/5
      float rad = 0.6324555320f * sinf(arg) * invx;       // sqrt(2/5)*sin/x
      z += rad * (W1[r * 64 + tid] * 0.3535533906f);      // W1/sqrt(8)
    }
    float sg = 1.0f / (1.0f + expf(-z));
    hsh[tid] = 1.679177f * z * sg;
  }
  __syncthreads();
  float acc = 0.0f;
  for (int j = 0; j < 64; ++j)
    acc += hsh[j] * W2[j * HIDDEN + tid];
  acc *= 0.125f;                                          // W2/8
  const ushort_t a16 = f2h(acc);
  TqB[((size_t)i * HIDDEN + tid) * 2] = a16;              // lo slot of row i
  if (i >= 1)
    TqB[((size_t)(i - 1) * HIDDEN + tid) * 2 + 1] = a16;  // hi slot of row i-1
}

// ---------------- K1b: pack node_attrs f32 -> fp16x2 (halves gather traffic) ----
__global__ __launch_bounds__(256) void attrs_pack(const float* __restrict__ attrs,
                                                  unsigned* __restrict__ attrsB,
                                                  int n2) {
  const int i = blockIdx.x * 256 + threadIdx.x;
  if (i < n2) {
    const float2 v = ((const float2*)attrs)[i];
    attrsB[i] = pack2h(v.x, v.y);
  }
}

// ---------------- K2a: per-block exclusive scan (1024 elems/block) ----------------
__global__ __launch_bounds__(1024) void scan_blocks(const int* __restrict__ cnt,
                                                    int* __restrict__ partial,
                                                    int* __restrict__ bsums, int n) {
  __shared__ int buf[1024];
  const int t = threadIdx.x;
  const int i = blockIdx.x * 1024 + t;
  const int v = (i < n) ? cnt[i] : 0;
  buf[t] = v;
  __syncthreads();
  for (int d = 1; d < 1024; d <<= 1) {
    const int x = buf[t];
    const int y = (t >= d) ? buf[t - d] : 0;
    __syncthreads();
    buf[t] = x + y;
    __syncthreads();
  }
  if (i < n) partial[i] = buf[t] - v;          // block-local exclusive
  if (t == 1023) bsums[blockIdx.x] = buf[1023];
}

// ---------------- K2b: single-block scan of block sums; writes off[n]=total ------
__global__ __launch_bounds__(1024) void scan_sums(int* __restrict__ bsums, int nb,
                                                  int* __restrict__ off, int n) {
  __shared__ int buf[1024];
  const int t = threadIdx.x;
  const int v = (t < nb) ? bsums[t] : 0;
  buf[t] = v;
  __syncthreads();
  for (int d = 1; d < 1024; d <<= 1) {
    const int x = buf[t];
    const int y = (t >= d) ? buf[t - d] : 0;
    __syncthreads();
    buf[t] = x + y;
    __syncthreads();
  }
  if (t < nb) bsums[t] = buf[t] - v;           // exclusive block offsets
  if (t == nb - 1) off[n] = buf[t];            // grand total
}

// ---------------- K2c: off/cur = partial + block offset ----------------
__global__ __launch_bounds__(256) void scan_final(const int* __restrict__ partial,
                                                  const int* __restrict__ bsums,
                                                  int* __restrict__ off,
                                                  int* __restrict__ cur, int n) {
  const int i = blockIdx.x * 256 + threadIdx.x;
  if (i < n) {
    const int o = partial[i] + bsums[i >> 10];
    off[i] = o;
    cur[i] = o;
  }
}

// ---------------- K3: build sorted 32B edge records ----------------
__global__ void scatter_kernel(const int* __restrict__ eidx,
                               const float* __restrict__ evec,
                               const float* __restrict__ elen,
                               int* __restrict__ cur, float4* __restrict__ recs,
                               int n_edges) {
  const int e = blockIdx.x * blockDim.x + threadIdx.x;
  if (e >= n_edges) return;
  const int s = eidx[e], r = eidx[n_edges + e];
  const float x = elen[e];
  const float v0 = evec[3 * e], v1 = evec[3 * e + 1], v2 = evec[3 * e + 2];
  const float rn = rsqrtf(v0 * v0 + v1 * v1 + v2 * v2);
  const float u = x * ((float)TBINS / 5.0f);
  int i0 = (int)floorf(u);
  i0 = i0 < 0 ? 0 : (i0 > TBINS - 1 ? TBINS - 1 : i0);
  const float fr = u - (float)i0;
  const bool valid = (x > 0.0f) && (x < 5.0f);
  const float w0 = valid ? 1.0f - fr : 0.0f;
  const float w1 = valid ? fr : 0.0f;
  const int pos = atomicAdd(&cur[r], 1);
  recs[2 * pos]     = make_float4(__int_as_float(s), w0, w1, __int_as_float(i0));
  recs[2 * pos + 1] = make_float4(1.7320508076f * v1 * rn,   // unit[:, [1,2,0]]*sqrt3
                                  1.7320508076f * v2 * rn,
                                  1.7320508076f * v0 * rn, 0.0f);
}

// ---------------- K4: pre-scale weights -> single fp16 in MFMA B-frag order ----
// P ushort layout: W0f[16384] W1f[8192] Wmf[24576]  (96 KB total)
// frag element: P[base + ((nt*KF+q)*64 + lane)*8 + j] = W[(quad*8+j) + q*32][nt*16+col]
// Wm carries an extra 2^8 to compensate B0 stored as B0*2^-8 (fp16 overflow headroom).
__global__ __launch_bounds__(256) void pack_weights(
    const float* __restrict__ W0, const float* __restrict__ W1,
    const float* __restrict__ Wm, ushort_t* __restrict__ P) {
  const int idx = blockIdx.x * 256 + threadIdx.x;     // 0..49151
  const int j = idx & 7, lane = (idx >> 3) & 63;
  const int krow = (lane >> 4) * 8 + j, col = lane & 15;
  float v;
  if (idx < 16384) {
    const int tq = idx >> 9, nt = tq >> 2, q = tq & 3;
    v = W0[(krow + q * 32) * HIDDEN + nt * 16 + col] * 0.0883883476f;
  } else if (idx < 24576) {
    const int i2 = idx - 16384;
    const int tq = i2 >> 9, nt = tq >> 2, q = tq & 3;
    v = W1[(krow + q * 32) * MUL1 + nt * 16 + col] * 0.0883883476f;
  } else {
    const int i3 = idx - 24576;
    const int tq = i3 >> 9, nt = tq / 6, q = tq % 6;
    v = Wm[(krow + q * 32) * HIDDEN + nt * 16 + col] * 18.4752086f;  // 0.07217*256
  }
  P[idx] = f2h(v);
}

// ---------------- K5: pure gather: per node accumulate S (128) and G (128x3),
// write 1KB fp16 record.
__global__ __launch_bounds__(1024) void node_sg(
    const unsigned* __restrict__ attrsB, const unsigned* __restrict__ TqB,
    const float4* __restrict__ recs, const int* __restrict__ off,
    unsigned* __restrict__ SG, int n_nodes) {
  const int lane = threadIdx.x & 63;
  const int wid = (blockIdx.x << 4) + (threadIdx.x >> 6);
  const int nw = gridDim.x << 4;
  for (int n = wid; n < n_nodes; n += nw) {
    const int beg = off[n], end = off[n + 1];
    float Sa = 0.f, Sb = 0.f;
    float Ga0 = 0.f, Ga1 = 0.f, Ga2 = 0.f, Gb0 = 0.f, Gb1 = 0.f, Gb2 = 0.f;
    for (int i = beg; i < end; i += 2) {
#pragma unroll
      for (int b = 0; b < 2; ++b) {
        const bool ok = (i + b) < end;
        const int idx = ok ? (i + b) : beg;       // clamp; zeroed via weights
        const float4 ra = recs[2 * idx];
        const float4 rb = recs[2 * idx + 1];
        const int s = __float_as_int(ra.x);
        const float w0 = ok ? ra.y : 0.f;
        const float w1v = ok ? ra.z : 0.f;
        const int i0 = __float_as_int(ra.w);
        const uint2 tq = *(const uint2*)&TqB[(size_t)i0 * HIDDEN + 2 * lane];  // u32 units
        const unsigned av = attrsB[(size_t)s * 64 + lane];
        const float Ra = w0 * hlo(tq.x) + w1v * hhi(tq.x);  // lerp ch 2l
        const float Rb = w0 * hlo(tq.y) + w1v * hhi(tq.y);  // lerp ch 2l+1
        const float la = hlo(av) * Ra, lb = hhi(av) * Rb;
        Sa += la; Sb += lb;
        Ga0 += la * rb.x; Ga1 += la * rb.y; Ga2 += la * rb.z;
        Gb0 += lb * rb.x; Gb1 += lb * rb.y; Gb2 += lb * rb.z;
      }
    }
    unsigned* srow = SG + (size_t)n * 256;        // 256 u32 = 512 fp16 per node
    srow[lane]       = pack2h(Sa, Sb);            // S[2l], S[2l+1]
    srow[64 + lane]  = pack2h(Ga0, Gb0);          // G_d0
    srow[128 + lane] = pack2h(Ga1, Gb1);          // G_d1
    srow[192 + lane] = pack2h(Ga2, Gb2);          // G_d2
  }
}

// ---------------- K6: wave-per-16-nodes MFMA (fp16 single precision):
// A0=S@W0', A1=G@W1', B0, c0+=B0@Wm'. 1-wave blocks; depth-3 register
// prefetch on the L2-resident P stream; no barrier (wave-private LDS,
// lgkmcnt ordering only); A1 stored as 12B dwordx3.
struct F3 { float x, y, z; };

__global__ __launch_bounds__(64, 2) void node_mfma(
    const ushort_t* __restrict__ SG, const ushort_t* __restrict__ P,
    float* __restrict__ out, int n_nodes) {
  __shared__ float B0s[16][196];      // B0 stage; stride 196 dw (2-way = free)
  const int lane = threadIdx.x & 63;
  const int tile = blockIdx.x;
  const int row = lane & 15, quad = lane >> 4;
  const int nA = min(tile * 16 + row, n_nodes - 1);   // clamped A-row node
  const ushort_t* sgA = SG + (size_t)nA * 512;
  const int cnode0 = tile * 16 + quad * 4;            // C-frag rows

  const ushort_t* W0f = P;            // 16384
  const ushort_t* W1f = P + 16384;    // 8192
  const ushort_t* Wmf = P + 24576;    // 24576

  // ---- A-side fragments (issued up front; S row + 3 G rows)
  f16x8 aS[4], aG[3][4];
#pragma unroll
  for (int q = 0; q < 4; ++q)
    aS[q] = *(const f16x8*)(sgA + quad * 8 + q * 32);
#pragma unroll
  for (int d = 0; d < 3; ++d)
#pragma unroll
    for (int q = 0; q < 4; ++q)
      aG[d][q] = *(const f16x8*)(sgA + 128 + d * 128 + quad * 8 + q * 32);

  f32x4 c0[8];
#pragma unroll
  for (int nt = 0; nt < 8; ++nt) c0[nt] = (f32x4){0.f, 0.f, 0.f, 0.f};
  f32x4 c1[3][4];
#pragma unroll
  for (int d = 0; d < 3; ++d)
#pragma unroll
    for (int nt = 0; nt < 4; ++nt) c1[d][nt] = (f32x4){0.f, 0.f, 0.f, 0.f};

  // ---- Phase 1: A0 = S @ W0' (M=16, N=128, K=128). depth-3 prefetch.
  {
    f16x8 pb[3][4];
#pragma unroll
    for (int nt = 0; nt < 2; ++nt)
#pragma unroll
      for (int q = 0; q < 4; ++q)
        pb[nt][q] = *(const f16x8*)(W0f + ((nt * 4 + q) * 64 + lane) * 8);
#pragma unroll
    for (int nt = 0; nt < 8; ++nt) {
      const int cur = nt % 3;
      if (nt < 6) {
        const int dst = (nt + 2) % 3;
#pragma unroll
        for (int q = 0; q < 4; ++q)
          pb[dst][q] = *(const f16x8*)(W0f + (((nt + 2) * 4 + q) * 64 + lane) * 8);
      }
#pragma unroll
      for (int q = 0; q < 4; ++q)
        c0[nt] = __builtin_amdgcn_mfma_f32_16x16x32_f16(aS[q], pb[cur][q], c0[nt], 0, 0, 0);
    }
  }

  // ---- Phase 2: A1_d = G_d @ W1' (3 x [M=16, N=64, K=128]). depth-3 prefetch.
  {
    f16x8 pb[3][4];
#pragma unroll
    for (int nt = 0; nt < 2; ++nt)
#pragma unroll
      for (int q = 0; q < 4; ++q)
        pb[nt][q] = *(const f16x8*)(W1f + ((nt * 4 + q) * 64 + lane) * 8);
#pragma unroll
    for (int nt = 0; nt < 4; ++nt) {
      const int cur = nt % 3;
      if (nt < 2) {
        const int dst = (nt + 2) % 3;
#pragma unroll
        for (int q = 0; q < 4; ++q)
          pb[dst][q] = *(const f16x8*)(W1f + (((nt + 2) * 4 + q) * 64 + lane) * 8);
      }
#pragma unroll
      for (int q = 0; q < 4; ++q)
#pragma unroll
        for (int d = 0; d < 3; ++d)
          c1[d][nt] = __builtin_amdgcn_mfma_f32_16x16x32_f16(aG[d][q], pb[cur][q], c1[d][nt], 0, 0, 0);
    }
  }

  // ---- store A1 (out cols 128+3m+d) as one 12B store per (nt,r)
#pragma unroll
  for (int nt = 0; nt < 4; ++nt) {
    const int m = nt * 16 + row;
#pragma unroll
    for (int r = 0; r < 4; ++r) {
      const int n = cnode0 + r;
      if (n < n_nodes) {
        F3 v3 = {c1[0][nt][r], c1[1][nt][r], c1[2][nt][r]};
        *(F3*)&out[(size_t)n * ACOLS + HIDDEN + 3 * m] = v3;
      }
    }
  }

  // ---- build B0*2^-8 in LDS (C-layout -> A-layout transpose via LDS).
  // 2^-4 on the linear value before squaring = exact 2^-8 on B0; compensated
  // by the 2^8 baked into Wmf. Keeps fp16 A-frags far from 65504.
#pragma unroll
  for (int nt = 0; nt < 8; ++nt)
#pragma unroll
    for (int r = 0; r < 4; ++r) {
      const float a = c0[nt][r] * 0.0625f;
      B0s[quad * 4 + r][nt * 16 + row] = a * a;
    }
#pragma unroll
  for (int nt = 0; nt < 4; ++nt)
#pragma unroll
    for (int r = 0; r < 4; ++r) {
      const float x = c1[0][nt][r] * 0.0625f, y = c1[1][nt][r] * 0.0625f,
                  z = c1[2][nt][r] * 0.0625f;
      B0s[quad * 4 + r][HIDDEN + nt * 16 + row] =
          (x * x + y * y + z * z) * 0.5773502692f;   // /sqrt(3), *2^-8
    }

  // ---- Phase 3: c0 += B0 @ Wm' (K=192). Issue q=0/1 B-frag loads BEFORE the
  // LDS wait so they fly during the A-side cvt work.
  f16x8 mh[3][8];
#pragma unroll
  for (int qq = 0; qq < 2; ++qq)
#pragma unroll
    for (int nt = 0; nt < 8; ++nt)
      mh[qq][nt] = *(const f16x8*)(Wmf + ((nt * 6 + qq) * 64 + lane) * 8);

  // wave-private LDS: only this wave's ds_writes must complete (no barrier,
  // keeps the global prefetches above in flight). sched_barrier pins order.
  asm volatile("s_waitcnt lgkmcnt(0)" ::: "memory");
  __builtin_amdgcn_sched_barrier(0);

  f16x8 ahq[6];
#pragma unroll
  for (int q = 0; q < 6; ++q) {
    const float* src = &B0s[row][quad * 8 + q * 32];
#pragma unroll
    for (int j = 0; j < 8; ++j) ahq[q][j] = (_Float16)src[j];
  }
#pragma unroll
  for (int q = 0; q < 6; ++q) {
    const int cur = q % 3;
    if (q < 4) {
      const int dst = (q + 2) % 3;
#pragma unroll
      for (int nt = 0; nt < 8; ++nt)
        mh[dst][nt] = *(const f16x8*)(Wmf + ((nt * 6 + (q + 2)) * 64 + lane) * 8);
    }
#pragma unroll
    for (int nt = 0; nt < 8; ++nt)
      c0[nt] = __builtin_amdgcn_mfma_f32_16x16x32_f16(ahq[q], mh[cur][nt], c0[nt], 0, 0, 0);
  }

  // ---- store out[:, :128] = A0 + mix0 (64B-coalesced per quad group)
#pragma unroll
  for (int nt = 0; nt < 8; ++nt)
#pragma unroll
    for (int r = 0; r < 4; ++r) {
      const int n = cnode0 + r;
      if (n < n_nodes) out[(size_t)n * ACOLS + nt * 16 + row] = c0[nt][r];
    }
}

extern "C" void kernel_launch(void* const* d_in, const int* in_sizes, int n_in,
                              void* d_out, int out_size, void* d_ws, size_t ws_size,
                              hipStream_t stream) {
  const float* attrs = (const float*)d_in[0];
  const int*   eidx  = (const int*)d_in[1];
  const float* evec  = (const float*)d_in[2];
  const float* elen  = (const float*)d_in[3];
  const float* W1    = (const float*)d_in[4];
  const float* W2    = (const float*)d_in[5];
  const float* Wtp0  = (const float*)d_in[6];
  const float* Wtp1  = (const float*)d_in[7];
  const float* Wmix  = (const float*)d_in[8];
  float* out = (float*)d_out;

  const int n_nodes = in_sizes[0] / HIDDEN;
  const int n_edges = in_sizes[1] / 2;

  // ws: recs | TqB | cnt | off | cur | partial | bsums | SG(1KB/node) | P(96KB) | attrsB
  char* ws = (char*)d_ws;
  float4* recs = (float4*)ws;
  size_t o1 = (((size_t)n_edges * 32) + 255) & ~(size_t)255;
  ushort_t* TqB = (ushort_t*)(ws + o1);                       // (TBINS+1)*128 u32
  size_t o2 = (o1 + (size_t)(TBINS + 1) * HIDDEN * 4 + 255) & ~(size_t)255;
  int* cnt = (int*)(ws + o2);
  size_t o3 = (o2 + (size_t)n_nodes * 4 + 255) & ~(size_t)255;
  int* off = (int*)(ws + o3);
  size_t o4 = (o3 + (size_t)(n_nodes + 1) * 4 + 255) & ~(size_t)255;
  int* cur = (int*)(ws + o4);
  size_t o5 = (o4 + (size_t)n_nodes * 4 + 255) & ~(size_t)255;
  int* partial = (int*)(ws + o5);
  size_t o6 = (o5 + (size_t)n_nodes * 4 + 255) & ~(size_t)255;
  int* bsums = (int*)(ws + o6);
  size_t o7 = (o6 + 1024 * 4 + 255) & ~(size_t)255;
  unsigned* SG = (unsigned*)(ws + o7);
  size_t o8 = o7 + (size_t)n_nodes * 1024;
  ushort_t* P = (ushort_t*)(ws + o8);
  size_t o9 = (o8 + 49152 * 2 + 255) & ~(size_t)255;
  unsigned* attrsB = (unsigned*)(ws + o9);                    // n_nodes*64 u32

  (void)hipMemsetAsync(cnt, 0, (size_t)n_nodes * 4, stream);
  const int n2 = n_nodes * 64;
  attrs_pack<<<(n2 + 255) / 256, 256, 0, stream>>>(attrs, attrsB, n2);
  const int hist_blocks = (n_edges + 127) / 128;
  tab_hist<<<TBINS + 1 + hist_blocks, 128, 0, stream>>>(W1, W2, TqB,
                                                        eidx + n_edges, cnt, n_edges);
  const int nscan = (n_nodes + 1023) / 1024;
  scan_blocks<<<nscan, 1024, 0, stream>>>(cnt, partial, bsums, n_nodes);
  scan_sums<<<1, 1024, 0, stream>>>(bsums, nscan, off, n_nodes);
  scan_final<<<(n_nodes + 255) / 256, 256, 0, stream>>>(partial, bsums, off, cur,
                                                        n_nodes);
  scatter_kernel<<<(n_edges + 255) / 256, 256, 0, stream>>>(eidx, evec, elen, cur,
                                                            recs, n_edges);
  pack_weights<<<192, 256, 0, stream>>>(Wtp0, Wtp1, Wmix, P);
  node_sg<<<512, 1024, 0, stream>>>(attrsB, (const unsigned*)TqB, recs, off, SG,
                                    n_nodes);
  const int ntiles = (n_nodes + 15) / 16;
  node_mfma<<<ntiles, 64, 0, stream>>>((const ushort_t*)SG, P, out, n_nodes);
}